// Round 5
// baseline (318.217 us; speedup 1.0000x reference)
//
#include <hip/hip_runtime.h>

#define B_SZ 8
#define N1 8192
#define N2 2048
#define C1 128
#define C2 256
#define CIN 384
#define M0 256
#define NP (B_SZ * N1)   // 65536
#define CHUNKS 8
#define CHUNK (N2 / CHUNKS)   // 256
#define ASTRIDE 392          // A-tile LDS row stride in bf16 (384+8): rows offset 4 banks -> 2-way max

typedef __bf16 bf16_t;
typedef bf16_t bf16x8 __attribute__((ext_vector_type(8)));
typedef bf16_t bf16x4 __attribute__((ext_vector_type(4)));
typedef bf16_t bf16x2 __attribute__((ext_vector_type(2)));
typedef float  f32x4  __attribute__((ext_vector_type(4)));

// ---------------- fp32 -> bf16 weight convert ----------------
__global__ void cvt_bf16_kernel(const float* __restrict__ in, bf16_t* __restrict__ out, int n) {
    int i = blockIdx.x * 256 + threadIdx.x;
    if (i < n) out[i] = (bf16_t)in[i];
}

// ---------------- 3-NN partial: squared-distance compare, SoA partial output ----------------
// grid: dim3(B*N1/256, CHUNKS); block = 256 queries x 256-candidate chunk.
// pd/pi layout: pd[(c*3+r)*NP + p] -> coalesced stores here, coalesced loads in merge.
__global__ __launch_bounds__(256) void nn3_partial_kernel(const float* __restrict__ xyz1,
                                                          const float* __restrict__ xyz2,
                                                          float* __restrict__ pd,
                                                          int* __restrict__ pi) {
    __shared__ float4 s2[CHUNK];   // 4 KB: x,y,z,|p|^2
    int b = blockIdx.x >> 5;
    int i = ((blockIdx.x & 31) << 8) + threadIdx.x;
    int c = blockIdx.y;
    const float* x2 = xyz2 + ((size_t)b * N2 + (size_t)c * CHUNK) * 3;
    {
        int j = threadIdx.x;
        float x = x2[j * 3 + 0], y = x2[j * 3 + 1], z = x2[j * 3 + 2];
        s2[j] = make_float4(x, y, z, x * x + y * y + z * z);
    }
    __syncthreads();
    const float* p = xyz1 + ((size_t)b * N1 + i) * 3;
    float px = p[0], py = p[1], pz = p[2];
    float pn = px * px + py * py + pz * pz;
    float d0 = 1e30f, d1 = 1e30f, d2 = 1e30f;   // squared distances
    int   j0 = 0,     j1 = 0,     j2 = 0;
#pragma unroll 4
    for (int j = 0; j < CHUNK; ++j) {
        float4 v = s2[j];
        float dot = fmaf(px, v.x, fmaf(py, v.y, pz * v.z));
        float sq  = fmaf(-2.0f, dot, pn + v.w);   // order-preserving vs sqrt(clamp(sq))
        bool c0 = sq < d0, c1 = sq < d1, c2 = sq < d2;
        d2 = c1 ? d1 : (c2 ? sq : d2);
        j2 = c1 ? j1 : (c2 ? j  : j2);
        d1 = c0 ? d0 : (c1 ? sq : d1);
        j1 = c0 ? j0 : (c1 ? j  : j1);
        d0 = c0 ? sq : d0;
        j0 = c0 ? j  : j0;
    }
    int jb = c * CHUNK;
    size_t pidx = (size_t)b * N1 + i;
    pd[((size_t)c * 3 + 0) * NP + pidx] = d0;
    pd[((size_t)c * 3 + 1) * NP + pidx] = d1;
    pd[((size_t)c * 3 + 2) * NP + pidx] = d2;
    pi[((size_t)c * 3 + 0) * NP + pidx] = j0 + jb;
    pi[((size_t)c * 3 + 1) * NP + pidx] = j1 + jb;
    pi[((size_t)c * 3 + 2) * NP + pidx] = j2 + jb;
}

// ---------------- merge 8 partial top-3 (SoA, coalesced), then sqrt + weights ----------------
__global__ void nn3_merge_kernel(const float* __restrict__ pd, const int* __restrict__ pi,
                                 int* __restrict__ idx3, float* __restrict__ w3) {
    int p = blockIdx.x * 256 + threadIdx.x;
    float d0 = 1e30f, d1 = 1e30f, d2 = 1e30f;
    int   j0 = 0,     j1 = 0,     j2 = 0;
    // k = c*3+r: chunk-major, rank-ascending — same scan order as AoS version (stable ties)
#pragma unroll
    for (int k = 0; k < CHUNKS * 3; ++k) {
        float d = pd[(size_t)k * NP + p];
        int   j = pi[(size_t)k * NP + p];
        bool c0 = d < d0, c1 = d < d1, c2 = d < d2;
        d2 = c1 ? d1 : (c2 ? d : d2);
        j2 = c1 ? j1 : (c2 ? j : j2);
        d1 = c0 ? d0 : (c1 ? d : d1);
        j1 = c0 ? j0 : (c1 ? j : j1);
        d0 = c0 ? d : d0;
        j0 = c0 ? j : j0;
    }
    float r0 = sqrtf(fmaxf(d0, 0.0f));
    float r1 = sqrtf(fmaxf(d1, 0.0f));
    float r2 = sqrtf(fmaxf(d2, 0.0f));
    float inv0 = 1.0f / (r0 + 1e-8f);
    float inv1 = 1.0f / (r1 + 1e-8f);
    float inv2 = 1.0f / (r2 + 1e-8f);
    float s = inv0 + inv1 + inv2;
    size_t o = (size_t)p * 3;
    w3[o] = inv0 / s; w3[o + 1] = inv1 / s; w3[o + 2] = inv2 / s;
    idx3[o] = j0; idx3[o + 1] = j1; idx3[o + 2] = j2;
}

// ---------------- GEMM1 fused with gather: build A-tile (64 x 384 bf16) in LDS, then MFMA ----
// grid: NP/64 = 1024 blocks, 512 thr = 8 waves (2 row-groups x 4 col-groups), wave tile 32x64.
__global__ __launch_bounds__(512) void gemm1_fused_kernel(const float* __restrict__ points1,
                                                          const float* __restrict__ points2,
                                                          const int* __restrict__ idx3,
                                                          const float* __restrict__ w3,
                                                          const bf16_t* __restrict__ Wt,
                                                          bf16_t* __restrict__ H,
                                                          float* __restrict__ sum,
                                                          float* __restrict__ sumsq) {
    __shared__ bf16_t As[64 * ASTRIDE];      // ~49 KB
    __shared__ float lsum[256], lssq[256];   // +2 KB
    int row0 = blockIdx.x * 64;              // first point of this tile
    // ---- phase 1: gather/interp/concat into LDS (8 threads per point) ----
    {
        int pt  = threadIdx.x >> 3;          // 0..63
        int sub = threadIdx.x & 7;           // 0..7
        int p   = row0 + pt;
        int b   = p >> 13;
        const int*   id = idx3 + (size_t)p * 3;
        const float* w  = w3  + (size_t)p * 3;
        int   i0 = id[0], i1 = id[1], i2 = id[2];
        float w0 = w[0],  w1 = w[1],  w2 = w[2];
        const float* P2 = points2 + (size_t)b * N2 * C2;
        const float* r0 = P2 + (size_t)i0 * C2;
        const float* r1 = P2 + (size_t)i1 * C2;
        const float* r2 = P2 + (size_t)i2 * C2;
        bf16_t* Ar = As + pt * ASTRIDE;
        // interp channels: 8 subs x 32 ch
        int c0 = sub * 32;
#pragma unroll
        for (int q = 0; q < 8; ++q) {
            int c = c0 + q * 4;
            float4 a  = *(const float4*)(r0 + c);
            float4 bb = *(const float4*)(r1 + c);
            float4 cc = *(const float4*)(r2 + c);
            bf16x4 o;
            o[0] = (bf16_t)(w0 * a.x + w1 * bb.x + w2 * cc.x);
            o[1] = (bf16_t)(w0 * a.y + w1 * bb.y + w2 * cc.y);
            o[2] = (bf16_t)(w0 * a.z + w1 * bb.z + w2 * cc.z);
            o[3] = (bf16_t)(w0 * a.w + w1 * bb.w + w2 * cc.w);
            *(bf16x4*)(Ar + c) = o;
        }
        // points1 channels: 8 subs x 16 ch
        const float* p1 = points1 + (size_t)p * C1 + sub * 16;
#pragma unroll
        for (int q = 0; q < 4; ++q) {
            float4 v = *(const float4*)(p1 + q * 4);
            bf16x4 o;
            o[0] = (bf16_t)v.x; o[1] = (bf16_t)v.y; o[2] = (bf16_t)v.z; o[3] = (bf16_t)v.w;
            *(bf16x4*)(Ar + C2 + sub * 16 + q * 4) = o;
        }
    }
    if (threadIdx.x < 256) { lsum[threadIdx.x] = 0.0f; lssq[threadIdx.x] = 0.0f; }
    __syncthreads();
    // ---- phase 2: MFMA ----
    int wave = threadIdx.x >> 6;
    int lane = threadIdx.x & 63;
    int wr = wave >> 2, wc = wave & 3;       // 2 x 4 wave grid
    int l15  = lane & 15;
    int quad = lane >> 4;
    f32x4 acc[2][4] = {};
    const bf16_t* Wp = Wt + ((size_t)(wc * 64) + l15) * CIN + quad * 8;
    const bf16_t* Alds = As + (wr * 32 + l15) * ASTRIDE + quad * 8;
    for (int k0 = 0; k0 < CIN; k0 += 32) {
        bf16x8 a[2], bfr[4];
#pragma unroll
        for (int mi = 0; mi < 2; ++mi) a[mi] = *(const bf16x8*)(Alds + mi * 16 * ASTRIDE + k0);
#pragma unroll
        for (int ni = 0; ni < 4; ++ni) bfr[ni] = *(const bf16x8*)(Wp + (size_t)ni * 16 * CIN + k0);
#pragma unroll
        for (int mi = 0; mi < 2; ++mi)
#pragma unroll
            for (int ni = 0; ni < 4; ++ni)
                acc[mi][ni] = __builtin_amdgcn_mfma_f32_16x16x32_bf16(a[mi], bfr[ni], acc[mi][ni], 0, 0, 0);
    }
    // ---- epilogue: bf16 store + column stats. C/D: col=lane&15, row=quad*4+reg ----
#pragma unroll
    for (int mi = 0; mi < 2; ++mi)
#pragma unroll
        for (int ni = 0; ni < 4; ++ni) {
            int col  = wc * 64 + ni * 16 + l15;
            int rowb = row0 + wr * 32 + mi * 16 + quad * 4;
#pragma unroll
            for (int r = 0; r < 4; ++r)
                H[(size_t)(rowb + r) * 256 + col] = (bf16_t)acc[mi][ni][r];
        }
#pragma unroll
    for (int ni = 0; ni < 4; ++ni) {
        float s = 0.0f, ss = 0.0f;
#pragma unroll
        for (int mi = 0; mi < 2; ++mi)
#pragma unroll
            for (int r = 0; r < 4; ++r) {
                float v = acc[mi][ni][r];
                s += v; ss = fmaf(v, v, ss);
            }
        s  += __shfl_xor(s, 16);  s  += __shfl_xor(s, 32);
        ss += __shfl_xor(ss, 16); ss += __shfl_xor(ss, 32);
        if (quad == 0) {
            int cl = wc * 64 + ni * 16 + l15;
            atomicAdd(&lsum[cl], s);
            atomicAdd(&lssq[cl], ss);
        }
    }
    __syncthreads();
    if (threadIdx.x < 256) {
        atomicAdd(&sum[threadIdx.x],   lsum[threadIdx.x]);
        atomicAdd(&sumsq[threadIdx.x], lssq[threadIdx.x]);
    }
}

// ---------------- GEMM2: relu(bn(H0)) * W1^T -> H1 bf16 + column stats (BN fused in A-load) ----
__global__ __launch_bounds__(512) void gemm2_kernel(const bf16_t* __restrict__ A,
                                                    const bf16_t* __restrict__ Wt,
                                                    const float* __restrict__ scale,
                                                    const float* __restrict__ shift,
                                                    bf16_t* __restrict__ H,
                                                    float* __restrict__ sum,
                                                    float* __restrict__ sumsq) {
    const int K = M0;   // 256
    __shared__ float ssc[256], ssh[256];
    if (threadIdx.x < 256) { ssc[threadIdx.x] = scale[threadIdx.x]; ssh[threadIdx.x] = shift[threadIdx.x]; }
    __syncthreads();
    int wave = threadIdx.x >> 6;
    int lane = threadIdx.x & 63;
    int wr = wave >> 2, wc = wave & 3;
    int row0 = blockIdx.x * 128 + wr * 64;
    int col0 = wc * 64;
    int l15  = lane & 15;
    int quad = lane >> 4;
    f32x4 acc[4][4] = {};
    const bf16_t* Ap = A  + ((size_t)row0 + l15) * K + quad * 8;
    const bf16_t* Wp = Wt + ((size_t)col0 + l15) * K + quad * 8;
    for (int k0 = 0; k0 < K; k0 += 32) {
        int kb = k0 + quad * 8;
        float4 sc0 = *(const float4*)&ssc[kb], sc1 = *(const float4*)&ssc[kb + 4];
        float4 sh0 = *(const float4*)&ssh[kb], sh1 = *(const float4*)&ssh[kb + 4];
        bf16x8 a[4], bfr[4];
#pragma unroll
        for (int i = 0; i < 4; ++i) {
            bf16x8 raw = *(const bf16x8*)(Ap + (size_t)i * 16 * K + k0);
            bf16x8 t;
            t[0] = (bf16_t)fmaxf(fmaf((float)raw[0], sc0.x, sh0.x), 0.0f);
            t[1] = (bf16_t)fmaxf(fmaf((float)raw[1], sc0.y, sh0.y), 0.0f);
            t[2] = (bf16_t)fmaxf(fmaf((float)raw[2], sc0.z, sh0.z), 0.0f);
            t[3] = (bf16_t)fmaxf(fmaf((float)raw[3], sc0.w, sh0.w), 0.0f);
            t[4] = (bf16_t)fmaxf(fmaf((float)raw[4], sc1.x, sh1.x), 0.0f);
            t[5] = (bf16_t)fmaxf(fmaf((float)raw[5], sc1.y, sh1.y), 0.0f);
            t[6] = (bf16_t)fmaxf(fmaf((float)raw[6], sc1.z, sh1.z), 0.0f);
            t[7] = (bf16_t)fmaxf(fmaf((float)raw[7], sc1.w, sh1.w), 0.0f);
            a[i] = t;
        }
#pragma unroll
        for (int i = 0; i < 4; ++i) bfr[i] = *(const bf16x8*)(Wp + (size_t)i * 16 * K + k0);
#pragma unroll
        for (int mi = 0; mi < 4; ++mi)
#pragma unroll
            for (int ni = 0; ni < 4; ++ni)
                acc[mi][ni] = __builtin_amdgcn_mfma_f32_16x16x32_bf16(a[mi], bfr[ni], acc[mi][ni], 0, 0, 0);
    }
#pragma unroll
    for (int mi = 0; mi < 4; ++mi)
#pragma unroll
        for (int ni = 0; ni < 4; ++ni) {
            int col  = col0 + ni * 16 + l15;
            int rowb = row0 + mi * 16 + quad * 4;
#pragma unroll
            for (int r = 0; r < 4; ++r)
                H[(size_t)(rowb + r) * 256 + col] = (bf16_t)acc[mi][ni][r];
        }
    __shared__ float lsum[256], lssq[256];
    if (threadIdx.x < 256) { lsum[threadIdx.x] = 0.0f; lssq[threadIdx.x] = 0.0f; }
    __syncthreads();
#pragma unroll
    for (int ni = 0; ni < 4; ++ni) {
        float s = 0.0f, ss = 0.0f;
#pragma unroll
        for (int mi = 0; mi < 4; ++mi)
#pragma unroll
            for (int r = 0; r < 4; ++r) {
                float v = acc[mi][ni][r];
                s += v; ss = fmaf(v, v, ss);
            }
        s  += __shfl_xor(s, 16);  s  += __shfl_xor(s, 32);
        ss += __shfl_xor(ss, 16); ss += __shfl_xor(ss, 32);
        if (quad == 0) {
            int cl = col0 + ni * 16 + l15;
            atomicAdd(&lsum[cl], s);
            atomicAdd(&lssq[cl], ss);
        }
    }
    __syncthreads();
    if (threadIdx.x < 256) {
        atomicAdd(&sum[threadIdx.x],   lsum[threadIdx.x]);
        atomicAdd(&sumsq[threadIdx.x], lssq[threadIdx.x]);
    }
}

// ---------------- BN stats -> scale/shift ----------------
__global__ void finalize_kernel(const float* __restrict__ sum, const float* __restrict__ sumsq,
                                const float* __restrict__ gamma, const float* __restrict__ beta,
                                float* __restrict__ scale, float* __restrict__ shift) {
    int c = threadIdx.x;
    float m   = sum[c]   * (1.0f / NP);
    float var = sumsq[c] * (1.0f / NP) - m * m;
    float sc  = rsqrtf(var + 1e-5f) * gamma[c];
    scale[c] = sc;
    shift[c] = fmaf(-m, sc, beta[c]);
}

// ---------------- final BN+ReLU: H1 bf16 -> fp32 d_out ----------------
__global__ void bnrelu_final_kernel(const bf16_t* __restrict__ H, const float* __restrict__ scale,
                                    const float* __restrict__ shift, float* __restrict__ out) {
    int tid = blockIdx.x * 256 + threadIdx.x;   // one tid = 8 elements
    bf16x8 v = *(const bf16x8*)(H + (size_t)tid * 8);
    int c = (tid & 31) * 8;
    float4 o0, o1;
    o0.x = fmaxf(fmaf((float)v[0], scale[c + 0], shift[c + 0]), 0.0f);
    o0.y = fmaxf(fmaf((float)v[1], scale[c + 1], shift[c + 1]), 0.0f);
    o0.z = fmaxf(fmaf((float)v[2], scale[c + 2], shift[c + 2]), 0.0f);
    o0.w = fmaxf(fmaf((float)v[3], scale[c + 3], shift[c + 3]), 0.0f);
    o1.x = fmaxf(fmaf((float)v[4], scale[c + 4], shift[c + 4]), 0.0f);
    o1.y = fmaxf(fmaf((float)v[5], scale[c + 5], shift[c + 5]), 0.0f);
    o1.z = fmaxf(fmaf((float)v[6], scale[c + 6], shift[c + 6]), 0.0f);
    o1.w = fmaxf(fmaf((float)v[7], scale[c + 7], shift[c + 7]), 0.0f);
    ((float4*)out)[tid * 2]     = o0;
    ((float4*)out)[tid * 2 + 1] = o1;
}

extern "C" void kernel_launch(void* const* d_in, const int* in_sizes, int n_in,
                              void* d_out, int out_size, void* d_ws, size_t ws_size,
                              hipStream_t stream) {
    const float* xyz1    = (const float*)d_in[0];
    const float* xyz2    = (const float*)d_in[1];
    const float* points1 = (const float*)d_in[2];
    const float* points2 = (const float*)d_in[3];
    const float* W0      = (const float*)d_in[4];
    const float* g0      = (const float*)d_in[5];
    const float* b0      = (const float*)d_in[6];
    const float* W1      = (const float*)d_in[7];
    const float* g1      = (const float*)d_in[8];
    const float* b1      = (const float*)d_in[9];
    float* out = (float*)d_out;

    // ws layout (float offsets), total ~81.6 MB
    float* wsf    = (float*)d_ws;
    float* s0     = wsf + 0;
    float* ss0    = wsf + 256;
    float* s1     = wsf + 512;
    float* ss1    = wsf + 768;
    float* scale0 = wsf + 1024;
    float* shift0 = wsf + 1280;
    float* scale1 = wsf + 1536;
    float* shift1 = wsf + 1792;
    float* w3     = wsf + 2048;                       // 196608 f
    int*   idx3   = (int*)(wsf + 198656);             // 196608 i
    bf16_t* Wb0   = (bf16_t*)(wsf + 395264);          // 98304 bf16 (49152 f)
    bf16_t* Wb1   = (bf16_t*)(wsf + 444416);          // 65536 bf16 (32768 f)
    float* pd     = wsf + 477184;                     // NP*24 f (SoA; dead after merge)
    int*   pi     = (int*)(wsf + 2050048);            // NP*24 i
    bf16_t* H0    = (bf16_t*)(wsf + 3622912);         // NP*256 bf16 (8388608 f)
    bf16_t* H1    = (bf16_t*)(wsf + 12011520);        // NP*256 bf16 (8388608 f) -> ends 20400128 f

    hipMemsetAsync(wsf, 0, 1024 * sizeof(float), stream);   // zero stat accumulators

    cvt_bf16_kernel<<<(M0 * CIN + 255) / 256, 256, 0, stream>>>(W0, Wb0, M0 * CIN);
    cvt_bf16_kernel<<<(M0 * M0 + 255) / 256, 256, 0, stream>>>(W1, Wb1, M0 * M0);

    nn3_partial_kernel<<<dim3(B_SZ * (N1 / 256), CHUNKS), 256, 0, stream>>>(xyz1, xyz2, pd, pi);
    nn3_merge_kernel<<<NP / 256, 256, 0, stream>>>(pd, pi, idx3, w3);

    // layer 0: fused gather + GEMM (+stats) -> H0 bf16; finalize
    gemm1_fused_kernel<<<NP / 64, 512, 0, stream>>>(points1, points2, idx3, w3, Wb0, H0, s0, ss0);
    finalize_kernel<<<1, 256, 0, stream>>>(s0, ss0, g0, b0, scale0, shift0);

    // layer 1: GEMM with fused BN+ReLU on A (+stats) -> H1 bf16; finalize
    gemm2_kernel<<<NP / 128, 512, 0, stream>>>(H0, Wb1, scale0, shift0, H1, s1, ss1);
    finalize_kernel<<<1, 256, 0, stream>>>(s1, ss1, g1, b1, scale1, shift1);

    // final BN+ReLU -> fp32 output
    bnrelu_final_kernel<<<NP * 256 / 8 / 256, 256, 0, stream>>>(H1, scale1, shift1, out);
}

// Round 6
// 300.470 us; speedup vs baseline: 1.0591x; 1.0591x over previous
//
#include <hip/hip_runtime.h>

#define B_SZ 8
#define N1 8192
#define N2 2048
#define C1 128
#define C2 256
#define CIN 384
#define M0 256
#define NP (B_SZ * N1)   // 65536
#define CHUNKS 8
#define CHUNK (N2 / CHUNKS)   // 256
#define ASTRIDE 392          // A-tile LDS row stride in bf16 (384+8)

typedef __bf16 bf16_t;
typedef bf16_t bf16x8 __attribute__((ext_vector_type(8)));
typedef bf16_t bf16x4 __attribute__((ext_vector_type(4)));
typedef bf16_t bf16x2 __attribute__((ext_vector_type(2)));
typedef float  f32x4  __attribute__((ext_vector_type(4)));

// ---------------- fp32 -> bf16 weight convert ----------------
__global__ void cvt_bf16_kernel(const float* __restrict__ in, bf16_t* __restrict__ out, int n) {
    int i = blockIdx.x * 256 + threadIdx.x;
    if (i < n) out[i] = (bf16_t)in[i];
}

// ---------------- 3-NN partial: squared-distance compare, SoA partial output ----------------
__global__ __launch_bounds__(256) void nn3_partial_kernel(const float* __restrict__ xyz1,
                                                          const float* __restrict__ xyz2,
                                                          float* __restrict__ pd,
                                                          int* __restrict__ pi) {
    __shared__ float4 s2[CHUNK];   // 4 KB: x,y,z,|p|^2
    int b = blockIdx.x >> 5;
    int i = ((blockIdx.x & 31) << 8) + threadIdx.x;
    int c = blockIdx.y;
    const float* x2 = xyz2 + ((size_t)b * N2 + (size_t)c * CHUNK) * 3;
    {
        int j = threadIdx.x;
        float x = x2[j * 3 + 0], y = x2[j * 3 + 1], z = x2[j * 3 + 2];
        s2[j] = make_float4(x, y, z, x * x + y * y + z * z);
    }
    __syncthreads();
    const float* p = xyz1 + ((size_t)b * N1 + i) * 3;
    float px = p[0], py = p[1], pz = p[2];
    float pn = px * px + py * py + pz * pz;
    float d0 = 1e30f, d1 = 1e30f, d2 = 1e30f;   // squared distances
    int   j0 = 0,     j1 = 0,     j2 = 0;
#pragma unroll 4
    for (int j = 0; j < CHUNK; ++j) {
        float4 v = s2[j];
        float dot = fmaf(px, v.x, fmaf(py, v.y, pz * v.z));
        float sq  = fmaf(-2.0f, dot, pn + v.w);   // order-preserving vs sqrt(clamp(sq))
        bool c0 = sq < d0, c1 = sq < d1, c2 = sq < d2;
        d2 = c1 ? d1 : (c2 ? sq : d2);
        j2 = c1 ? j1 : (c2 ? j  : j2);
        d1 = c0 ? d0 : (c1 ? sq : d1);
        j1 = c0 ? j0 : (c1 ? j  : j1);
        d0 = c0 ? sq : d0;
        j0 = c0 ? j  : j0;
    }
    int jb = c * CHUNK;
    size_t pidx = (size_t)b * N1 + i;
    pd[((size_t)c * 3 + 0) * NP + pidx] = d0;
    pd[((size_t)c * 3 + 1) * NP + pidx] = d1;
    pd[((size_t)c * 3 + 2) * NP + pidx] = d2;
    pi[((size_t)c * 3 + 0) * NP + pidx] = j0 + jb;
    pi[((size_t)c * 3 + 1) * NP + pidx] = j1 + jb;
    pi[((size_t)c * 3 + 2) * NP + pidx] = j2 + jb;
}

// ---------------- merge 8 partial top-3 (SoA, coalesced), then sqrt + weights ----------------
__global__ void nn3_merge_kernel(const float* __restrict__ pd, const int* __restrict__ pi,
                                 int* __restrict__ idx3, float* __restrict__ w3) {
    int p = blockIdx.x * 256 + threadIdx.x;
    float d0 = 1e30f, d1 = 1e30f, d2 = 1e30f;
    int   j0 = 0,     j1 = 0,     j2 = 0;
#pragma unroll
    for (int k = 0; k < CHUNKS * 3; ++k) {
        float d = pd[(size_t)k * NP + p];
        int   j = pi[(size_t)k * NP + p];
        bool c0 = d < d0, c1 = d < d1, c2 = d < d2;
        d2 = c1 ? d1 : (c2 ? d : d2);
        j2 = c1 ? j1 : (c2 ? j : j2);
        d1 = c0 ? d0 : (c1 ? d : d1);
        j1 = c0 ? j0 : (c1 ? j : j1);
        d0 = c0 ? d : d0;
        j0 = c0 ? j : j0;
    }
    float r0 = sqrtf(fmaxf(d0, 0.0f));
    float r1 = sqrtf(fmaxf(d1, 0.0f));
    float r2 = sqrtf(fmaxf(d2, 0.0f));
    float inv0 = 1.0f / (r0 + 1e-8f);
    float inv1 = 1.0f / (r1 + 1e-8f);
    float inv2 = 1.0f / (r2 + 1e-8f);
    float s = inv0 + inv1 + inv2;
    size_t o = (size_t)p * 3;
    w3[o] = inv0 / s; w3[o + 1] = inv1 / s; w3[o + 2] = inv2 / s;
    idx3[o] = j0; idx3[o + 1] = j1; idx3[o + 2] = j2;
}

// ---------------- GEMM1 fused with gather ----------------
// grid: NP/64 = 1024 blocks. Batch->XCD swizzle: batch = blk&7 (round-robin XCD dispatch
// keeps each XCD's points2 working set at one 2MB batch slice, L2-resident).
// Phase 1 coalesced: per q, the 8 sub-threads of a point read contiguous 128B.
__global__ __launch_bounds__(512) void gemm1_fused_kernel(const float* __restrict__ points1,
                                                          const float* __restrict__ points2,
                                                          const int* __restrict__ idx3,
                                                          const float* __restrict__ w3,
                                                          const bf16_t* __restrict__ Wt,
                                                          bf16_t* __restrict__ H,
                                                          float* __restrict__ sum,
                                                          float* __restrict__ sumsq) {
    __shared__ bf16_t As[64 * ASTRIDE];      // ~49 KB
    __shared__ float lsum[256], lssq[256];   // +2 KB
    int bb   = blockIdx.x & 7;               // batch == XCD affinity
    int tile = blockIdx.x >> 3;              // 0..127 within batch
    int row0 = bb * N1 + tile * 64;          // first point of this tile
    // ---- phase 1: gather/interp/concat into LDS (8 threads per point) ----
    {
        int pt  = threadIdx.x >> 3;          // 0..63
        int sub = threadIdx.x & 7;           // 0..7
        int p   = row0 + pt;
        const int*   id = idx3 + (size_t)p * 3;
        const float* w  = w3  + (size_t)p * 3;
        int   i0 = id[0], i1 = id[1], i2 = id[2];
        float w0 = w[0],  w1 = w[1],  w2 = w[2];
        const float* P2 = points2 + (size_t)bb * N2 * C2;
        const float* r0 = P2 + (size_t)i0 * C2;
        const float* r1 = P2 + (size_t)i1 * C2;
        const float* r2 = P2 + (size_t)i2 * C2;
        bf16_t* Ar = As + pt * ASTRIDE;
        // interp channels: per q, subs cover contiguous 128B of each gathered row
#pragma unroll
        for (int q = 0; q < 8; ++q) {
            int c = q * 32 + sub * 4;
            float4 a  = *(const float4*)(r0 + c);
            float4 bb4 = *(const float4*)(r1 + c);
            float4 cc = *(const float4*)(r2 + c);
            bf16x4 o;
            o[0] = (bf16_t)(w0 * a.x + w1 * bb4.x + w2 * cc.x);
            o[1] = (bf16_t)(w0 * a.y + w1 * bb4.y + w2 * cc.y);
            o[2] = (bf16_t)(w0 * a.z + w1 * bb4.z + w2 * cc.z);
            o[3] = (bf16_t)(w0 * a.w + w1 * bb4.w + w2 * cc.w);
            *(bf16x4*)(Ar + c) = o;
        }
        // points1 channels: same coalesced pattern
        const float* p1 = points1 + (size_t)p * C1;
#pragma unroll
        for (int q = 0; q < 4; ++q) {
            int c = q * 32 + sub * 4;
            float4 v = *(const float4*)(p1 + c);
            bf16x4 o;
            o[0] = (bf16_t)v.x; o[1] = (bf16_t)v.y; o[2] = (bf16_t)v.z; o[3] = (bf16_t)v.w;
            *(bf16x4*)(Ar + C2 + c) = o;
        }
    }
    if (threadIdx.x < 256) { lsum[threadIdx.x] = 0.0f; lssq[threadIdx.x] = 0.0f; }
    __syncthreads();
    // ---- phase 2: MFMA (8 waves = 2 row-groups x 4 col-groups, wave tile 32x64) ----
    int wave = threadIdx.x >> 6;
    int lane = threadIdx.x & 63;
    int wr = wave >> 2, wc = wave & 3;
    int l15  = lane & 15;
    int quad = lane >> 4;
    f32x4 acc[2][4] = {};
    const bf16_t* Wp = Wt + ((size_t)(wc * 64) + l15) * CIN + quad * 8;
    const bf16_t* Alds = As + (wr * 32 + l15) * ASTRIDE + quad * 8;
    for (int k0 = 0; k0 < CIN; k0 += 32) {
        bf16x8 a[2], bfr[4];
#pragma unroll
        for (int mi = 0; mi < 2; ++mi) a[mi] = *(const bf16x8*)(Alds + mi * 16 * ASTRIDE + k0);
#pragma unroll
        for (int ni = 0; ni < 4; ++ni) bfr[ni] = *(const bf16x8*)(Wp + (size_t)ni * 16 * CIN + k0);
#pragma unroll
        for (int mi = 0; mi < 2; ++mi)
#pragma unroll
            for (int ni = 0; ni < 4; ++ni)
                acc[mi][ni] = __builtin_amdgcn_mfma_f32_16x16x32_bf16(a[mi], bfr[ni], acc[mi][ni], 0, 0, 0);
    }
    // ---- epilogue: bf16 store + column stats. C/D: col=lane&15, row=quad*4+reg ----
#pragma unroll
    for (int mi = 0; mi < 2; ++mi)
#pragma unroll
        for (int ni = 0; ni < 4; ++ni) {
            int col  = wc * 64 + ni * 16 + l15;
            int rowb = row0 + wr * 32 + mi * 16 + quad * 4;
#pragma unroll
            for (int r = 0; r < 4; ++r)
                H[(size_t)(rowb + r) * 256 + col] = (bf16_t)acc[mi][ni][r];
        }
#pragma unroll
    for (int ni = 0; ni < 4; ++ni) {
        float s = 0.0f, ss = 0.0f;
#pragma unroll
        for (int mi = 0; mi < 2; ++mi)
#pragma unroll
            for (int r = 0; r < 4; ++r) {
                float v = acc[mi][ni][r];
                s += v; ss = fmaf(v, v, ss);
            }
        s  += __shfl_xor(s, 16);  s  += __shfl_xor(s, 32);
        ss += __shfl_xor(ss, 16); ss += __shfl_xor(ss, 32);
        if (quad == 0) {
            int cl = wc * 64 + ni * 16 + l15;
            atomicAdd(&lsum[cl], s);
            atomicAdd(&lssq[cl], ss);
        }
    }
    __syncthreads();
    if (threadIdx.x < 256) {
        atomicAdd(&sum[threadIdx.x],   lsum[threadIdx.x]);
        atomicAdd(&sumsq[threadIdx.x], lssq[threadIdx.x]);
    }
}

// ---------------- GEMM2: relu(bn(H0)) * W1^T -> H1 bf16 + column stats (BN fused in A-load) ----
__global__ __launch_bounds__(512) void gemm2_kernel(const bf16_t* __restrict__ A,
                                                    const bf16_t* __restrict__ Wt,
                                                    const float* __restrict__ scale,
                                                    const float* __restrict__ shift,
                                                    bf16_t* __restrict__ H,
                                                    float* __restrict__ sum,
                                                    float* __restrict__ sumsq) {
    const int K = M0;   // 256
    __shared__ float ssc[256], ssh[256];
    if (threadIdx.x < 256) { ssc[threadIdx.x] = scale[threadIdx.x]; ssh[threadIdx.x] = shift[threadIdx.x]; }
    __syncthreads();
    int wave = threadIdx.x >> 6;
    int lane = threadIdx.x & 63;
    int wr = wave >> 2, wc = wave & 3;
    int row0 = blockIdx.x * 128 + wr * 64;
    int col0 = wc * 64;
    int l15  = lane & 15;
    int quad = lane >> 4;
    f32x4 acc[4][4] = {};
    const bf16_t* Ap = A  + ((size_t)row0 + l15) * K + quad * 8;
    const bf16_t* Wp = Wt + ((size_t)col0 + l15) * K + quad * 8;
    for (int k0 = 0; k0 < K; k0 += 32) {
        int kb = k0 + quad * 8;
        float4 sc0 = *(const float4*)&ssc[kb], sc1 = *(const float4*)&ssc[kb + 4];
        float4 sh0 = *(const float4*)&ssh[kb], sh1 = *(const float4*)&ssh[kb + 4];
        bf16x8 a[4], bfr[4];
#pragma unroll
        for (int i = 0; i < 4; ++i) {
            bf16x8 raw = *(const bf16x8*)(Ap + (size_t)i * 16 * K + k0);
            bf16x8 t;
            t[0] = (bf16_t)fmaxf(fmaf((float)raw[0], sc0.x, sh0.x), 0.0f);
            t[1] = (bf16_t)fmaxf(fmaf((float)raw[1], sc0.y, sh0.y), 0.0f);
            t[2] = (bf16_t)fmaxf(fmaf((float)raw[2], sc0.z, sh0.z), 0.0f);
            t[3] = (bf16_t)fmaxf(fmaf((float)raw[3], sc0.w, sh0.w), 0.0f);
            t[4] = (bf16_t)fmaxf(fmaf((float)raw[4], sc1.x, sh1.x), 0.0f);
            t[5] = (bf16_t)fmaxf(fmaf((float)raw[5], sc1.y, sh1.y), 0.0f);
            t[6] = (bf16_t)fmaxf(fmaf((float)raw[6], sc1.z, sh1.z), 0.0f);
            t[7] = (bf16_t)fmaxf(fmaf((float)raw[7], sc1.w, sh1.w), 0.0f);
            a[i] = t;
        }
#pragma unroll
        for (int i = 0; i < 4; ++i) bfr[i] = *(const bf16x8*)(Wp + (size_t)i * 16 * K + k0);
#pragma unroll
        for (int mi = 0; mi < 4; ++mi)
#pragma unroll
            for (int ni = 0; ni < 4; ++ni)
                acc[mi][ni] = __builtin_amdgcn_mfma_f32_16x16x32_bf16(a[mi], bfr[ni], acc[mi][ni], 0, 0, 0);
    }
#pragma unroll
    for (int mi = 0; mi < 4; ++mi)
#pragma unroll
        for (int ni = 0; ni < 4; ++ni) {
            int col  = col0 + ni * 16 + l15;
            int rowb = row0 + mi * 16 + quad * 4;
#pragma unroll
            for (int r = 0; r < 4; ++r)
                H[(size_t)(rowb + r) * 256 + col] = (bf16_t)acc[mi][ni][r];
        }
    __shared__ float lsum[256], lssq[256];
    if (threadIdx.x < 256) { lsum[threadIdx.x] = 0.0f; lssq[threadIdx.x] = 0.0f; }
    __syncthreads();
#pragma unroll
    for (int ni = 0; ni < 4; ++ni) {
        float s = 0.0f, ss = 0.0f;
#pragma unroll
        for (int mi = 0; mi < 4; ++mi)
#pragma unroll
            for (int r = 0; r < 4; ++r) {
                float v = acc[mi][ni][r];
                s += v; ss = fmaf(v, v, ss);
            }
        s  += __shfl_xor(s, 16);  s  += __shfl_xor(s, 32);
        ss += __shfl_xor(ss, 16); ss += __shfl_xor(ss, 32);
        if (quad == 0) {
            int cl = col0 + ni * 16 + l15;
            atomicAdd(&lsum[cl], s);
            atomicAdd(&lssq[cl], ss);
        }
    }
    __syncthreads();
    if (threadIdx.x < 256) {
        atomicAdd(&sum[threadIdx.x],   lsum[threadIdx.x]);
        atomicAdd(&sumsq[threadIdx.x], lssq[threadIdx.x]);
    }
}

// ---------------- BN stats -> scale/shift ----------------
__global__ void finalize_kernel(const float* __restrict__ sum, const float* __restrict__ sumsq,
                                const float* __restrict__ gamma, const float* __restrict__ beta,
                                float* __restrict__ scale, float* __restrict__ shift) {
    int c = threadIdx.x;
    float m   = sum[c]   * (1.0f / NP);
    float var = sumsq[c] * (1.0f / NP) - m * m;
    float sc  = rsqrtf(var + 1e-5f) * gamma[c];
    scale[c] = sc;
    shift[c] = fmaf(-m, sc, beta[c]);
}

// ---------------- final BN+ReLU: H1 bf16 -> fp32 d_out ----------------
__global__ void bnrelu_final_kernel(const bf16_t* __restrict__ H, const float* __restrict__ scale,
                                    const float* __restrict__ shift, float* __restrict__ out) {
    int tid = blockIdx.x * 256 + threadIdx.x;   // one tid = 8 elements
    bf16x8 v = *(const bf16x8*)(H + (size_t)tid * 8);
    int c = (tid & 31) * 8;
    float4 o0, o1;
    o0.x = fmaxf(fmaf((float)v[0], scale[c + 0], shift[c + 0]), 0.0f);
    o0.y = fmaxf(fmaf((float)v[1], scale[c + 1], shift[c + 1]), 0.0f);
    o0.z = fmaxf(fmaf((float)v[2], scale[c + 2], shift[c + 2]), 0.0f);
    o0.w = fmaxf(fmaf((float)v[3], scale[c + 3], shift[c + 3]), 0.0f);
    o1.x = fmaxf(fmaf((float)v[4], scale[c + 4], shift[c + 4]), 0.0f);
    o1.y = fmaxf(fmaf((float)v[5], scale[c + 5], shift[c + 5]), 0.0f);
    o1.z = fmaxf(fmaf((float)v[6], scale[c + 6], shift[c + 6]), 0.0f);
    o1.w = fmaxf(fmaf((float)v[7], scale[c + 7], shift[c + 7]), 0.0f);
    ((float4*)out)[tid * 2]     = o0;
    ((float4*)out)[tid * 2 + 1] = o1;
}

extern "C" void kernel_launch(void* const* d_in, const int* in_sizes, int n_in,
                              void* d_out, int out_size, void* d_ws, size_t ws_size,
                              hipStream_t stream) {
    const float* xyz1    = (const float*)d_in[0];
    const float* xyz2    = (const float*)d_in[1];
    const float* points1 = (const float*)d_in[2];
    const float* points2 = (const float*)d_in[3];
    const float* W0      = (const float*)d_in[4];
    const float* g0      = (const float*)d_in[5];
    const float* b0      = (const float*)d_in[6];
    const float* W1      = (const float*)d_in[7];
    const float* g1      = (const float*)d_in[8];
    const float* b1      = (const float*)d_in[9];
    float* out = (float*)d_out;

    // ws layout (float offsets), total ~81.6 MB
    float* wsf    = (float*)d_ws;
    float* s0     = wsf + 0;
    float* ss0    = wsf + 256;
    float* s1     = wsf + 512;
    float* ss1    = wsf + 768;
    float* scale0 = wsf + 1024;
    float* shift0 = wsf + 1280;
    float* scale1 = wsf + 1536;
    float* shift1 = wsf + 1792;
    float* w3     = wsf + 2048;                       // 196608 f
    int*   idx3   = (int*)(wsf + 198656);             // 196608 i
    bf16_t* Wb0   = (bf16_t*)(wsf + 395264);          // 98304 bf16 (49152 f)
    bf16_t* Wb1   = (bf16_t*)(wsf + 444416);          // 65536 bf16 (32768 f)
    float* pd     = wsf + 477184;                     // NP*24 f (SoA; dead after merge)
    int*   pi     = (int*)(wsf + 2050048);            // NP*24 i
    bf16_t* H0    = (bf16_t*)(wsf + 3622912);         // NP*256 bf16 (8388608 f)
    bf16_t* H1    = (bf16_t*)(wsf + 12011520);        // NP*256 bf16 (8388608 f)

    hipMemsetAsync(wsf, 0, 1024 * sizeof(float), stream);   // zero stat accumulators

    cvt_bf16_kernel<<<(M0 * CIN + 255) / 256, 256, 0, stream>>>(W0, Wb0, M0 * CIN);
    cvt_bf16_kernel<<<(M0 * M0 + 255) / 256, 256, 0, stream>>>(W1, Wb1, M0 * M0);

    nn3_partial_kernel<<<dim3(B_SZ * (N1 / 256), CHUNKS), 256, 0, stream>>>(xyz1, xyz2, pd, pi);
    nn3_merge_kernel<<<NP / 256, 256, 0, stream>>>(pd, pi, idx3, w3);

    // layer 0: fused gather + GEMM (+stats) -> H0 bf16; finalize
    gemm1_fused_kernel<<<NP / 64, 512, 0, stream>>>(points1, points2, idx3, w3, Wb0, H0, s0, ss0);
    finalize_kernel<<<1, 256, 0, stream>>>(s0, ss0, g0, b0, scale0, shift0);

    // layer 1: GEMM with fused BN+ReLU on A (+stats) -> H1 bf16; finalize
    gemm2_kernel<<<NP / 128, 512, 0, stream>>>(H0, Wb1, scale0, shift0, H1, s1, ss1);
    finalize_kernel<<<1, 256, 0, stream>>>(s1, ss1, g1, b1, scale1, shift1);

    // final BN+ReLU -> fp32 output
    bnrelu_final_kernel<<<NP * 256 / 8 / 256, 256, 0, stream>>>(H1, scale1, shift1, out);
}

// Round 7
// 288.614 us; speedup vs baseline: 1.1026x; 1.0411x over previous
//
#include <hip/hip_runtime.h>

#define B_SZ 8
#define N1 8192
#define N2 2048
#define C1 128
#define C2 256
#define CIN 384
#define M0 256
#define NP (B_SZ * N1)   // 65536
#define CHUNKS 8
#define CHUNK (N2 / CHUNKS)   // 256
#define ASTRIDE 392          // A-tile LDS row stride in bf16 (384+8)

typedef __bf16 bf16_t;
typedef bf16_t bf16x8 __attribute__((ext_vector_type(8)));
typedef bf16_t bf16x4 __attribute__((ext_vector_type(4)));
typedef float  f32x4  __attribute__((ext_vector_type(4)));

// ---------------- fp32 -> bf16 weight convert ----------------
__global__ void cvt_bf16_kernel(const float* __restrict__ in, bf16_t* __restrict__ out, int n) {
    int i = blockIdx.x * 256 + threadIdx.x;
    if (i < n) out[i] = (bf16_t)in[i];
}

// ---------------- 3-NN partial: squared-distance compare, SoA partial output ----------------
__global__ __launch_bounds__(256) void nn3_partial_kernel(const float* __restrict__ xyz1,
                                                          const float* __restrict__ xyz2,
                                                          float* __restrict__ pd,
                                                          int* __restrict__ pi) {
    __shared__ float4 s2[CHUNK];   // 4 KB: x,y,z,|p|^2
    int b = blockIdx.x >> 5;
    int i = ((blockIdx.x & 31) << 8) + threadIdx.x;
    int c = blockIdx.y;
    const float* x2 = xyz2 + ((size_t)b * N2 + (size_t)c * CHUNK) * 3;
    {
        int j = threadIdx.x;
        float x = x2[j * 3 + 0], y = x2[j * 3 + 1], z = x2[j * 3 + 2];
        s2[j] = make_float4(x, y, z, x * x + y * y + z * z);
    }
    __syncthreads();
    const float* p = xyz1 + ((size_t)b * N1 + i) * 3;
    float px = p[0], py = p[1], pz = p[2];
    float pn = px * px + py * py + pz * pz;
    float d0 = 1e30f, d1 = 1e30f, d2 = 1e30f;   // squared distances
    int   j0 = 0,     j1 = 0,     j2 = 0;
#pragma unroll 4
    for (int j = 0; j < CHUNK; ++j) {
        float4 v = s2[j];
        float dot = fmaf(px, v.x, fmaf(py, v.y, pz * v.z));
        float sq  = fmaf(-2.0f, dot, pn + v.w);   // order-preserving vs sqrt(clamp(sq))
        bool c0 = sq < d0, c1 = sq < d1, c2 = sq < d2;
        d2 = c1 ? d1 : (c2 ? sq : d2);
        j2 = c1 ? j1 : (c2 ? j  : j2);
        d1 = c0 ? d0 : (c1 ? sq : d1);
        j1 = c0 ? j0 : (c1 ? j  : j1);
        d0 = c0 ? sq : d0;
        j0 = c0 ? j  : j0;
    }
    int jb = c * CHUNK;
    size_t pidx = (size_t)b * N1 + i;
    pd[((size_t)c * 3 + 0) * NP + pidx] = d0;
    pd[((size_t)c * 3 + 1) * NP + pidx] = d1;
    pd[((size_t)c * 3 + 2) * NP + pidx] = d2;
    pi[((size_t)c * 3 + 0) * NP + pidx] = j0 + jb;
    pi[((size_t)c * 3 + 1) * NP + pidx] = j1 + jb;
    pi[((size_t)c * 3 + 2) * NP + pidx] = j2 + jb;
}

// ---------------- merge 8 partial top-3 (SoA, coalesced), then sqrt + weights ----------------
__global__ void nn3_merge_kernel(const float* __restrict__ pd, const int* __restrict__ pi,
                                 int* __restrict__ idx3, float* __restrict__ w3) {
    int p = blockIdx.x * 256 + threadIdx.x;
    float d0 = 1e30f, d1 = 1e30f, d2 = 1e30f;
    int   j0 = 0,     j1 = 0,     j2 = 0;
#pragma unroll
    for (int k = 0; k < CHUNKS * 3; ++k) {
        float d = pd[(size_t)k * NP + p];
        int   j = pi[(size_t)k * NP + p];
        bool c0 = d < d0, c1 = d < d1, c2 = d < d2;
        d2 = c1 ? d1 : (c2 ? d : d2);
        j2 = c1 ? j1 : (c2 ? j : j2);
        d1 = c0 ? d0 : (c1 ? d : d1);
        j1 = c0 ? j0 : (c1 ? j : j1);
        d0 = c0 ? d : d0;
        j0 = c0 ? j : j0;
    }
    float r0 = sqrtf(fmaxf(d0, 0.0f));
    float r1 = sqrtf(fmaxf(d1, 0.0f));
    float r2 = sqrtf(fmaxf(d2, 0.0f));
    float inv0 = 1.0f / (r0 + 1e-8f);
    float inv1 = 1.0f / (r1 + 1e-8f);
    float inv2 = 1.0f / (r2 + 1e-8f);
    float s = inv0 + inv1 + inv2;
    size_t o = (size_t)p * 3;
    w3[o] = inv0 / s; w3[o + 1] = inv1 / s; w3[o + 2] = inv2 / s;
    idx3[o] = j0; idx3[o + 1] = j1; idx3[o + 2] = j2;
}

// ---------------- GEMM1 fused with gather; ATOMIC-FREE stats (per-block partials) ----------------
// grid: NP/64 = 1024 blocks; batch->XCD swizzle (batch = blk&7).
__global__ __launch_bounds__(512) void gemm1_fused_kernel(const float* __restrict__ points1,
                                                          const float* __restrict__ points2,
                                                          const int* __restrict__ idx3,
                                                          const float* __restrict__ w3,
                                                          const bf16_t* __restrict__ Wt,
                                                          bf16_t* __restrict__ H,
                                                          float* __restrict__ P0) {
    __shared__ bf16_t As[64 * ASTRIDE];      // ~49 KB
    __shared__ float lsum[256], lssq[256];   // +2 KB
    int bb   = blockIdx.x & 7;               // batch == XCD affinity
    int tile = blockIdx.x >> 3;
    int row0 = bb * N1 + tile * 64;
    // ---- phase 1: gather/interp/concat into LDS (8 threads per point, coalesced 128B runs) ----
    {
        int pt  = threadIdx.x >> 3;
        int sub = threadIdx.x & 7;
        int p   = row0 + pt;
        const int*   id = idx3 + (size_t)p * 3;
        const float* w  = w3  + (size_t)p * 3;
        int   i0 = id[0], i1 = id[1], i2 = id[2];
        float w0 = w[0],  w1 = w[1],  w2 = w[2];
        const float* P2 = points2 + (size_t)bb * N2 * C2;
        const float* r0 = P2 + (size_t)i0 * C2;
        const float* r1 = P2 + (size_t)i1 * C2;
        const float* r2 = P2 + (size_t)i2 * C2;
        bf16_t* Ar = As + pt * ASTRIDE;
#pragma unroll
        for (int q = 0; q < 8; ++q) {
            int c = q * 32 + sub * 4;
            float4 a   = *(const float4*)(r0 + c);
            float4 bb4 = *(const float4*)(r1 + c);
            float4 cc  = *(const float4*)(r2 + c);
            bf16x4 o;
            o[0] = (bf16_t)(w0 * a.x + w1 * bb4.x + w2 * cc.x);
            o[1] = (bf16_t)(w0 * a.y + w1 * bb4.y + w2 * cc.y);
            o[2] = (bf16_t)(w0 * a.z + w1 * bb4.z + w2 * cc.z);
            o[3] = (bf16_t)(w0 * a.w + w1 * bb4.w + w2 * cc.w);
            *(bf16x4*)(Ar + c) = o;
        }
        const float* p1 = points1 + (size_t)p * C1;
#pragma unroll
        for (int q = 0; q < 4; ++q) {
            int c = q * 32 + sub * 4;
            float4 v = *(const float4*)(p1 + c);
            bf16x4 o;
            o[0] = (bf16_t)v.x; o[1] = (bf16_t)v.y; o[2] = (bf16_t)v.z; o[3] = (bf16_t)v.w;
            *(bf16x4*)(Ar + C2 + c) = o;
        }
    }
    if (threadIdx.x < 256) { lsum[threadIdx.x] = 0.0f; lssq[threadIdx.x] = 0.0f; }
    __syncthreads();
    // ---- phase 2: MFMA (8 waves = 2 row-groups x 4 col-groups, wave tile 32x64) ----
    int wave = threadIdx.x >> 6;
    int lane = threadIdx.x & 63;
    int wr = wave >> 2, wc = wave & 3;
    int l15  = lane & 15;
    int quad = lane >> 4;
    f32x4 acc[2][4] = {};
    const bf16_t* Wp = Wt + ((size_t)(wc * 64) + l15) * CIN + quad * 8;
    const bf16_t* Alds = As + (wr * 32 + l15) * ASTRIDE + quad * 8;
    for (int k0 = 0; k0 < CIN; k0 += 32) {
        bf16x8 a[2], bfr[4];
#pragma unroll
        for (int mi = 0; mi < 2; ++mi) a[mi] = *(const bf16x8*)(Alds + mi * 16 * ASTRIDE + k0);
#pragma unroll
        for (int ni = 0; ni < 4; ++ni) bfr[ni] = *(const bf16x8*)(Wp + (size_t)ni * 16 * CIN + k0);
#pragma unroll
        for (int mi = 0; mi < 2; ++mi)
#pragma unroll
            for (int ni = 0; ni < 4; ++ni)
                acc[mi][ni] = __builtin_amdgcn_mfma_f32_16x16x32_bf16(a[mi], bfr[ni], acc[mi][ni], 0, 0, 0);
    }
    // ---- epilogue: bf16 store + per-block column stats (NO global atomics) ----
#pragma unroll
    for (int mi = 0; mi < 2; ++mi)
#pragma unroll
        for (int ni = 0; ni < 4; ++ni) {
            int col  = wc * 64 + ni * 16 + l15;
            int rowb = row0 + wr * 32 + mi * 16 + quad * 4;
#pragma unroll
            for (int r = 0; r < 4; ++r)
                H[(size_t)(rowb + r) * 256 + col] = (bf16_t)acc[mi][ni][r];
        }
#pragma unroll
    for (int ni = 0; ni < 4; ++ni) {
        float s = 0.0f, ss = 0.0f;
#pragma unroll
        for (int mi = 0; mi < 2; ++mi)
#pragma unroll
            for (int r = 0; r < 4; ++r) {
                float v = acc[mi][ni][r];
                s += v; ss = fmaf(v, v, ss);
            }
        s  += __shfl_xor(s, 16);  s  += __shfl_xor(s, 32);
        ss += __shfl_xor(ss, 16); ss += __shfl_xor(ss, 32);
        if (quad == 0) {
            int cl = wc * 64 + ni * 16 + l15;
            atomicAdd(&lsum[cl], s);     // LDS atomics only
            atomicAdd(&lssq[cl], ss);
        }
    }
    __syncthreads();
    if (threadIdx.x < 256) {
        float* slot = P0 + (size_t)blockIdx.x * 512;
        slot[threadIdx.x]       = lsum[threadIdx.x];   // coalesced plain stores
        slot[256 + threadIdx.x] = lssq[threadIdx.x];
    }
}

// ---------------- GEMM2: relu(bn(H0)) * W1^T -> H1 bf16; atomic-free stats ----------------
__global__ __launch_bounds__(512) void gemm2_kernel(const bf16_t* __restrict__ A,
                                                    const bf16_t* __restrict__ Wt,
                                                    const float* __restrict__ scale,
                                                    const float* __restrict__ shift,
                                                    bf16_t* __restrict__ H,
                                                    float* __restrict__ P1) {
    const int K = M0;   // 256
    __shared__ float ssc[256], ssh[256];
    __shared__ float lsum[256], lssq[256];
    if (threadIdx.x < 256) {
        ssc[threadIdx.x] = scale[threadIdx.x]; ssh[threadIdx.x] = shift[threadIdx.x];
        lsum[threadIdx.x] = 0.0f; lssq[threadIdx.x] = 0.0f;
    }
    __syncthreads();
    int wave = threadIdx.x >> 6;
    int lane = threadIdx.x & 63;
    int wr = wave >> 2, wc = wave & 3;
    int row0 = blockIdx.x * 128 + wr * 64;
    int col0 = wc * 64;
    int l15  = lane & 15;
    int quad = lane >> 4;
    f32x4 acc[4][4] = {};
    const bf16_t* Ap = A  + ((size_t)row0 + l15) * K + quad * 8;
    const bf16_t* Wp = Wt + ((size_t)col0 + l15) * K + quad * 8;
    for (int k0 = 0; k0 < K; k0 += 32) {
        int kb = k0 + quad * 8;
        float4 sc0 = *(const float4*)&ssc[kb], sc1 = *(const float4*)&ssc[kb + 4];
        float4 sh0 = *(const float4*)&ssh[kb], sh1 = *(const float4*)&ssh[kb + 4];
        bf16x8 a[4], bfr[4];
#pragma unroll
        for (int i = 0; i < 4; ++i) {
            bf16x8 raw = *(const bf16x8*)(Ap + (size_t)i * 16 * K + k0);
            bf16x8 t;
            t[0] = (bf16_t)fmaxf(fmaf((float)raw[0], sc0.x, sh0.x), 0.0f);
            t[1] = (bf16_t)fmaxf(fmaf((float)raw[1], sc0.y, sh0.y), 0.0f);
            t[2] = (bf16_t)fmaxf(fmaf((float)raw[2], sc0.z, sh0.z), 0.0f);
            t[3] = (bf16_t)fmaxf(fmaf((float)raw[3], sc0.w, sh0.w), 0.0f);
            t[4] = (bf16_t)fmaxf(fmaf((float)raw[4], sc1.x, sh1.x), 0.0f);
            t[5] = (bf16_t)fmaxf(fmaf((float)raw[5], sc1.y, sh1.y), 0.0f);
            t[6] = (bf16_t)fmaxf(fmaf((float)raw[6], sc1.z, sh1.z), 0.0f);
            t[7] = (bf16_t)fmaxf(fmaf((float)raw[7], sc1.w, sh1.w), 0.0f);
            a[i] = t;
        }
#pragma unroll
        for (int i = 0; i < 4; ++i) bfr[i] = *(const bf16x8*)(Wp + (size_t)i * 16 * K + k0);
#pragma unroll
        for (int mi = 0; mi < 4; ++mi)
#pragma unroll
            for (int ni = 0; ni < 4; ++ni)
                acc[mi][ni] = __builtin_amdgcn_mfma_f32_16x16x32_bf16(a[mi], bfr[ni], acc[mi][ni], 0, 0, 0);
    }
#pragma unroll
    for (int mi = 0; mi < 4; ++mi)
#pragma unroll
        for (int ni = 0; ni < 4; ++ni) {
            int col  = col0 + ni * 16 + l15;
            int rowb = row0 + mi * 16 + quad * 4;
#pragma unroll
            for (int r = 0; r < 4; ++r)
                H[(size_t)(rowb + r) * 256 + col] = (bf16_t)acc[mi][ni][r];
        }
#pragma unroll
    for (int ni = 0; ni < 4; ++ni) {
        float s = 0.0f, ss = 0.0f;
#pragma unroll
        for (int mi = 0; mi < 4; ++mi)
#pragma unroll
            for (int r = 0; r < 4; ++r) {
                float v = acc[mi][ni][r];
                s += v; ss = fmaf(v, v, ss);
            }
        s  += __shfl_xor(s, 16);  s  += __shfl_xor(s, 32);
        ss += __shfl_xor(ss, 16); ss += __shfl_xor(ss, 32);
        if (quad == 0) {
            int cl = col0 + ni * 16 + l15;
            atomicAdd(&lsum[cl], s);
            atomicAdd(&lssq[cl], ss);
        }
    }
    __syncthreads();
    if (threadIdx.x < 256) {
        float* slot = P1 + (size_t)blockIdx.x * 512;
        slot[threadIdx.x]       = lsum[threadIdx.x];
        slot[256 + threadIdx.x] = lssq[threadIdx.x];
    }
}

// ---------------- reduce per-block partials -> scale/shift (one block per channel) ----------------
__global__ __launch_bounds__(256) void finalize_partials_kernel(const float* __restrict__ P, int nblk,
                                                                const float* __restrict__ gamma,
                                                                const float* __restrict__ beta,
                                                                float* __restrict__ scale,
                                                                float* __restrict__ shift) {
    int c = blockIdx.x;
    float s = 0.0f, ss = 0.0f;
    for (int bb = threadIdx.x; bb < nblk; bb += 256) {
        const float* row = P + (size_t)bb * 512;
        s  += row[c];
        ss += row[256 + c];
    }
#pragma unroll
    for (int k = 32; k >= 1; k >>= 1) { s += __shfl_xor(s, k); ss += __shfl_xor(ss, k); }
    __shared__ float as_[4], ass_[4];
    int w = threadIdx.x >> 6;
    if ((threadIdx.x & 63) == 0) { as_[w] = s; ass_[w] = ss; }
    __syncthreads();
    if (threadIdx.x == 0) {
        float S  = as_[0] + as_[1] + as_[2] + as_[3];
        float SS = ass_[0] + ass_[1] + ass_[2] + ass_[3];
        float m   = S * (1.0f / NP);
        float var = SS * (1.0f / NP) - m * m;
        float sc  = rsqrtf(var + 1e-5f) * gamma[c];
        scale[c] = sc;
        shift[c] = fmaf(-m, sc, beta[c]);
    }
}

// ---------------- final BN+ReLU: H1 bf16 -> fp32 d_out ----------------
__global__ void bnrelu_final_kernel(const bf16_t* __restrict__ H, const float* __restrict__ scale,
                                    const float* __restrict__ shift, float* __restrict__ out) {
    int tid = blockIdx.x * 256 + threadIdx.x;   // one tid = 8 elements
    bf16x8 v = *(const bf16x8*)(H + (size_t)tid * 8);
    int c = (tid & 31) * 8;
    float4 o0, o1;
    o0.x = fmaxf(fmaf((float)v[0], scale[c + 0], shift[c + 0]), 0.0f);
    o0.y = fmaxf(fmaf((float)v[1], scale[c + 1], shift[c + 1]), 0.0f);
    o0.z = fmaxf(fmaf((float)v[2], scale[c + 2], shift[c + 2]), 0.0f);
    o0.w = fmaxf(fmaf((float)v[3], scale[c + 3], shift[c + 3]), 0.0f);
    o1.x = fmaxf(fmaf((float)v[4], scale[c + 4], shift[c + 4]), 0.0f);
    o1.y = fmaxf(fmaf((float)v[5], scale[c + 5], shift[c + 5]), 0.0f);
    o1.z = fmaxf(fmaf((float)v[6], scale[c + 6], shift[c + 6]), 0.0f);
    o1.w = fmaxf(fmaf((float)v[7], scale[c + 7], shift[c + 7]), 0.0f);
    ((float4*)out)[tid * 2]     = o0;
    ((float4*)out)[tid * 2 + 1] = o1;
}

extern "C" void kernel_launch(void* const* d_in, const int* in_sizes, int n_in,
                              void* d_out, int out_size, void* d_ws, size_t ws_size,
                              hipStream_t stream) {
    const float* xyz1    = (const float*)d_in[0];
    const float* xyz2    = (const float*)d_in[1];
    const float* points1 = (const float*)d_in[2];
    const float* points2 = (const float*)d_in[3];
    const float* W0      = (const float*)d_in[4];
    const float* g0      = (const float*)d_in[5];
    const float* b0      = (const float*)d_in[6];
    const float* W1      = (const float*)d_in[7];
    const float* g1      = (const float*)d_in[8];
    const float* b1      = (const float*)d_in[9];
    float* out = (float*)d_out;

    // ws layout (float offsets), total ~85 MB
    float* wsf    = (float*)d_ws;
    float* scale0 = wsf + 0;
    float* shift0 = wsf + 256;
    float* scale1 = wsf + 512;
    float* shift1 = wsf + 768;
    float* w3     = wsf + 2048;                       // 196608 f
    int*   idx3   = (int*)(wsf + 198656);             // 196608 i
    bf16_t* Wb0   = (bf16_t*)(wsf + 395264);          // 98304 bf16 (49152 f)
    bf16_t* Wb1   = (bf16_t*)(wsf + 444416);          // 65536 bf16 (32768 f)
    float* pd     = wsf + 477184;                     // NP*24 f (SoA; dead after merge)
    int*   pi     = (int*)(wsf + 2050048);            // NP*24 i
    bf16_t* H0    = (bf16_t*)(wsf + 3622912);         // NP*256 bf16 (8388608 f)
    bf16_t* H1    = (bf16_t*)(wsf + 12011520);        // NP*256 bf16 (8388608 f)
    float* P0     = wsf + 20400128;                   // 1024*512 f
    float* P1     = wsf + 20924416;                   // 512*512 f -> ends 21186560 f (~84.7MB)

    cvt_bf16_kernel<<<(M0 * CIN + 255) / 256, 256, 0, stream>>>(W0, Wb0, M0 * CIN);
    cvt_bf16_kernel<<<(M0 * M0 + 255) / 256, 256, 0, stream>>>(W1, Wb1, M0 * M0);

    nn3_partial_kernel<<<dim3(B_SZ * (N1 / 256), CHUNKS), 256, 0, stream>>>(xyz1, xyz2, pd, pi);
    nn3_merge_kernel<<<NP / 256, 256, 0, stream>>>(pd, pi, idx3, w3);

    // layer 0: fused gather + GEMM -> H0 bf16 + per-block partials; reduce -> scale0/shift0
    gemm1_fused_kernel<<<NP / 64, 512, 0, stream>>>(points1, points2, idx3, w3, Wb0, H0, P0);
    finalize_partials_kernel<<<256, 256, 0, stream>>>(P0, NP / 64, g0, b0, scale0, shift0);

    // layer 1: GEMM with fused BN+ReLU on A -> H1 bf16 + partials; reduce -> scale1/shift1
    gemm2_kernel<<<NP / 128, 512, 0, stream>>>(H0, Wb1, scale0, shift0, H1, P1);
    finalize_partials_kernel<<<256, 256, 0, stream>>>(P1, NP / 128, g1, b1, scale1, shift1);

    // final BN+ReLU -> fp32 output
    bnrelu_final_kernel<<<NP * 256 / 8 / 256, 256, 0, stream>>>(H1, scale1, shift1, out);
}

// Round 8
// 256.549 us; speedup vs baseline: 1.2404x; 1.1250x over previous
//
#include <hip/hip_runtime.h>

#define B_SZ 8
#define N1 8192
#define N2 2048
#define C1 128
#define C2 256
#define CIN 384
#define M0 256
#define NP (B_SZ * N1)   // 65536
#define CHUNKS 8
#define CHUNK (N2 / CHUNKS)   // 256
#define ASTRIDE 392          // gemm1 A-tile LDS row stride (384+8 bf16)
#define A2STRIDE 264         // gemm2 A-tile LDS row stride (256+8 bf16)

typedef __bf16 bf16_t;
typedef bf16_t bf16x8 __attribute__((ext_vector_type(8)));
typedef bf16_t bf16x4 __attribute__((ext_vector_type(4)));
typedef float  f32x4  __attribute__((ext_vector_type(4)));

// ---------------- fp32 -> bf16 converts ----------------
__global__ void cvt_bf16_kernel(const float* __restrict__ in, bf16_t* __restrict__ out, int n) {
    int i = blockIdx.x * 256 + threadIdx.x;
    if (i < n) out[i] = (bf16_t)in[i];
}
__global__ void cvt_bf16x4_kernel(const float* __restrict__ in, bf16_t* __restrict__ out) {
    int tid = blockIdx.x * 256 + threadIdx.x;
    float4 v = ((const float4*)in)[tid];
    bf16x4 o;
    o[0] = (bf16_t)v.x; o[1] = (bf16_t)v.y; o[2] = (bf16_t)v.z; o[3] = (bf16_t)v.w;
    ((bf16x4*)out)[tid] = o;
}

// ---------------- 3-NN partial: squared-distance compare, SoA output ----------------
__global__ __launch_bounds__(256) void nn3_partial_kernel(const float* __restrict__ xyz1,
                                                          const float* __restrict__ xyz2,
                                                          float* __restrict__ pd,
                                                          int* __restrict__ pi) {
    __shared__ float4 s2[CHUNK];   // 4 KB
    int b = blockIdx.x >> 5;
    int i = ((blockIdx.x & 31) << 8) + threadIdx.x;
    int c = blockIdx.y;
    const float* x2 = xyz2 + ((size_t)b * N2 + (size_t)c * CHUNK) * 3;
    {
        int j = threadIdx.x;
        float x = x2[j * 3 + 0], y = x2[j * 3 + 1], z = x2[j * 3 + 2];
        s2[j] = make_float4(x, y, z, x * x + y * y + z * z);
    }
    __syncthreads();
    const float* p = xyz1 + ((size_t)b * N1 + i) * 3;
    float px = p[0], py = p[1], pz = p[2];
    float pn = px * px + py * py + pz * pz;
    float d0 = 1e30f, d1 = 1e30f, d2 = 1e30f;
    int   j0 = 0,     j1 = 0,     j2 = 0;
#pragma unroll 4
    for (int j = 0; j < CHUNK; ++j) {
        float4 v = s2[j];
        float dot = fmaf(px, v.x, fmaf(py, v.y, pz * v.z));
        float sq  = fmaf(-2.0f, dot, pn + v.w);
        bool c0 = sq < d0, c1 = sq < d1, c2 = sq < d2;
        d2 = c1 ? d1 : (c2 ? sq : d2);
        j2 = c1 ? j1 : (c2 ? j  : j2);
        d1 = c0 ? d0 : (c1 ? sq : d1);
        j1 = c0 ? j0 : (c1 ? j  : j1);
        d0 = c0 ? sq : d0;
        j0 = c0 ? j  : j0;
    }
    int jb = c * CHUNK;
    size_t pidx = (size_t)b * N1 + i;
    pd[((size_t)c * 3 + 0) * NP + pidx] = d0;
    pd[((size_t)c * 3 + 1) * NP + pidx] = d1;
    pd[((size_t)c * 3 + 2) * NP + pidx] = d2;
    pi[((size_t)c * 3 + 0) * NP + pidx] = j0 + jb;
    pi[((size_t)c * 3 + 1) * NP + pidx] = j1 + jb;
    pi[((size_t)c * 3 + 2) * NP + pidx] = j2 + jb;
}

// ---------------- merge partials, sqrt + weights ----------------
__global__ void nn3_merge_kernel(const float* __restrict__ pd, const int* __restrict__ pi,
                                 int* __restrict__ idx3, float* __restrict__ w3) {
    int p = blockIdx.x * 256 + threadIdx.x;
    float d0 = 1e30f, d1 = 1e30f, d2 = 1e30f;
    int   j0 = 0,     j1 = 0,     j2 = 0;
#pragma unroll
    for (int k = 0; k < CHUNKS * 3; ++k) {
        float d = pd[(size_t)k * NP + p];
        int   j = pi[(size_t)k * NP + p];
        bool c0 = d < d0, c1 = d < d1, c2 = d < d2;
        d2 = c1 ? d1 : (c2 ? d : d2);
        j2 = c1 ? j1 : (c2 ? j : j2);
        d1 = c0 ? d0 : (c1 ? d : d1);
        j1 = c0 ? j0 : (c1 ? j : j1);
        d0 = c0 ? d : d0;
        j0 = c0 ? j : j0;
    }
    float r0 = sqrtf(fmaxf(d0, 0.0f));
    float r1 = sqrtf(fmaxf(d1, 0.0f));
    float r2 = sqrtf(fmaxf(d2, 0.0f));
    float inv0 = 1.0f / (r0 + 1e-8f);
    float inv1 = 1.0f / (r1 + 1e-8f);
    float inv2 = 1.0f / (r2 + 1e-8f);
    float s = inv0 + inv1 + inv2;
    size_t o = (size_t)p * 3;
    w3[o] = inv0 / s; w3[o + 1] = inv1 / s; w3[o + 2] = inv2 / s;
    idx3[o] = j0; idx3[o + 1] = j1; idx3[o + 2] = j2;
}

// ---------------- GEMM1 fused gather: bf16 points2, staged idx/w, 8 col-waves (W read 1x) ----
// grid NP/64 = 1024 blocks; batch->XCD swizzle (batch = blk&7).
__global__ __launch_bounds__(512) void gemm1_fused_kernel(const float* __restrict__ points1,
                                                          const bf16_t* __restrict__ P2b,
                                                          const int* __restrict__ idx3,
                                                          const float* __restrict__ w3,
                                                          const bf16_t* __restrict__ Wt,
                                                          bf16_t* __restrict__ H,
                                                          float* __restrict__ P0) {
    __shared__ bf16_t As[64 * ASTRIDE];   // 50176 B
    __shared__ int   si[192];             // 768 B
    __shared__ float sw[192];             // 768 B -> 51712 B total: 3 blocks/CU
    int bb   = blockIdx.x & 7;
    int tile = blockIdx.x >> 3;
    int row0 = bb * N1 + tile * 64;
    // stage idx/w coalesced
    if (threadIdx.x < 192)
        si[threadIdx.x] = idx3[(size_t)row0 * 3 + threadIdx.x];
    else if (threadIdx.x >= 256 && threadIdx.x < 448)
        sw[threadIdx.x - 256] = w3[(size_t)row0 * 3 + (threadIdx.x - 256)];
    __syncthreads();
    // ---- phase 1: interp (bf16 rows) + points1 copy into LDS; 8 threads/point ----
    {
        int pt  = threadIdx.x >> 3;
        int sub = threadIdx.x & 7;
        int i0 = si[pt * 3], i1 = si[pt * 3 + 1], i2 = si[pt * 3 + 2];
        float w0 = sw[pt * 3], w1 = sw[pt * 3 + 1], w2 = sw[pt * 3 + 2];
        const bf16_t* P2 = P2b + (size_t)bb * N2 * C2;
        const bf16_t* r0 = P2 + (size_t)i0 * C2;
        const bf16_t* r1 = P2 + (size_t)i1 * C2;
        const bf16_t* r2 = P2 + (size_t)i2 * C2;
        bf16_t* Ar = As + pt * ASTRIDE;
#pragma unroll
        for (int q = 0; q < 4; ++q) {
            int c = q * 64 + sub * 8;
            bf16x8 va = *(const bf16x8*)(r0 + c);
            bf16x8 vb = *(const bf16x8*)(r1 + c);
            bf16x8 vc = *(const bf16x8*)(r2 + c);
            bf16x8 o;
#pragma unroll
            for (int j = 0; j < 8; ++j)
                o[j] = (bf16_t)(w0 * (float)va[j] + w1 * (float)vb[j] + w2 * (float)vc[j]);
            *(bf16x8*)(Ar + c) = o;
        }
        const float* p1 = points1 + (size_t)(row0 + pt) * C1;
#pragma unroll
        for (int q = 0; q < 4; ++q) {
            int c = q * 32 + sub * 4;
            float4 v = *(const float4*)(p1 + c);
            bf16x4 o;
            o[0] = (bf16_t)v.x; o[1] = (bf16_t)v.y; o[2] = (bf16_t)v.z; o[3] = (bf16_t)v.w;
            *(bf16x4*)(Ar + C2 + c) = o;
        }
    }
    __syncthreads();
    // ---- phase 2: wave w -> cols [w*32, w*32+32), all 64 rows. W slice private to wave. ----
    int w    = threadIdx.x >> 6;
    int lane = threadIdx.x & 63;
    int l15  = lane & 15;
    int quad = lane >> 4;
    f32x4 acc[4][2] = {};
    const bf16_t* Wp = Wt + ((size_t)(w * 32) + l15) * CIN + quad * 8;
    const bf16_t* Al = As + l15 * ASTRIDE + quad * 8;
    for (int k0 = 0; k0 < CIN; k0 += 32) {
        bf16x8 bfr[2];
#pragma unroll
        for (int ni = 0; ni < 2; ++ni) bfr[ni] = *(const bf16x8*)(Wp + (size_t)ni * 16 * CIN + k0);
#pragma unroll
        for (int mi = 0; mi < 4; ++mi) {
            bf16x8 a = *(const bf16x8*)(Al + mi * 16 * ASTRIDE + k0);
            acc[mi][0] = __builtin_amdgcn_mfma_f32_16x16x32_bf16(a, bfr[0], acc[mi][0], 0, 0, 0);
            acc[mi][1] = __builtin_amdgcn_mfma_f32_16x16x32_bf16(a, bfr[1], acc[mi][1], 0, 0, 0);
        }
    }
    // ---- epilogue: H store + per-block column stats (each column owned by one lane) ----
#pragma unroll
    for (int mi = 0; mi < 4; ++mi)
#pragma unroll
        for (int ni = 0; ni < 2; ++ni) {
            int col  = w * 32 + ni * 16 + l15;
            int rowb = row0 + mi * 16 + quad * 4;
#pragma unroll
            for (int r = 0; r < 4; ++r)
                H[(size_t)(rowb + r) * 256 + col] = (bf16_t)acc[mi][ni][r];
        }
#pragma unroll
    for (int ni = 0; ni < 2; ++ni) {
        float s = 0.0f, ss = 0.0f;
#pragma unroll
        for (int mi = 0; mi < 4; ++mi)
#pragma unroll
            for (int r = 0; r < 4; ++r) {
                float v = acc[mi][ni][r];
                s += v; ss = fmaf(v, v, ss);
            }
        s  += __shfl_xor(s, 16);  s  += __shfl_xor(s, 32);
        ss += __shfl_xor(ss, 16); ss += __shfl_xor(ss, 32);
        if (quad == 0) {
            int cl = w * 32 + ni * 16 + l15;      // unique per lane across block
            float* slot = P0 + (size_t)blockIdx.x * 512;
            slot[cl]       = s;
            slot[256 + cl] = ss;
        }
    }
}

// ---------------- GEMM2: A staged in LDS with fused BN+ReLU (1x), 8 col-waves (W 1x) ----------
// grid NP/64 = 1024 blocks.
__global__ __launch_bounds__(512) void gemm2_kernel(const bf16_t* __restrict__ A,
                                                    const bf16_t* __restrict__ Wt,
                                                    const float* __restrict__ scale,
                                                    const float* __restrict__ shift,
                                                    bf16_t* __restrict__ H,
                                                    float* __restrict__ P1) {
    const int K = M0;   // 256
    __shared__ bf16_t As2[64 * A2STRIDE];   // 33792 B
    __shared__ float ssc[256], ssh[256];    // 2 KB
    int row0 = blockIdx.x * 64;
    if (threadIdx.x < 256) { ssc[threadIdx.x] = scale[threadIdx.x]; ssh[threadIdx.x] = shift[threadIdx.x]; }
    __syncthreads();
    // stage A-tile: 64 rows x 256 ch, BN+ReLU applied once; coalesced 16B loads
#pragma unroll
    for (int rI = 0; rI < 4; ++rI) {
        int idx = rI * 512 + threadIdx.x;     // 0..2047
        int row = idx >> 5;
        int c8  = (idx & 31) * 8;
        bf16x8 raw = *(const bf16x8*)(A + (size_t)(row0 + row) * 256 + c8);
        bf16x8 t;
#pragma unroll
        for (int j = 0; j < 8; ++j)
            t[j] = (bf16_t)fmaxf(fmaf((float)raw[j], ssc[c8 + j], ssh[c8 + j]), 0.0f);
        *(bf16x8*)(As2 + row * A2STRIDE + c8) = t;
    }
    __syncthreads();
    int w    = threadIdx.x >> 6;
    int lane = threadIdx.x & 63;
    int l15  = lane & 15;
    int quad = lane >> 4;
    f32x4 acc[4][2] = {};
    const bf16_t* Wp = Wt + ((size_t)(w * 32) + l15) * K + quad * 8;
    const bf16_t* Al = As2 + l15 * A2STRIDE + quad * 8;
    for (int k0 = 0; k0 < K; k0 += 32) {
        bf16x8 bfr[2];
#pragma unroll
        for (int ni = 0; ni < 2; ++ni) bfr[ni] = *(const bf16x8*)(Wp + (size_t)ni * 16 * K + k0);
#pragma unroll
        for (int mi = 0; mi < 4; ++mi) {
            bf16x8 a = *(const bf16x8*)(Al + mi * 16 * A2STRIDE + k0);
            acc[mi][0] = __builtin_amdgcn_mfma_f32_16x16x32_bf16(a, bfr[0], acc[mi][0], 0, 0, 0);
            acc[mi][1] = __builtin_amdgcn_mfma_f32_16x16x32_bf16(a, bfr[1], acc[mi][1], 0, 0, 0);
        }
    }
#pragma unroll
    for (int mi = 0; mi < 4; ++mi)
#pragma unroll
        for (int ni = 0; ni < 2; ++ni) {
            int col  = w * 32 + ni * 16 + l15;
            int rowb = row0 + mi * 16 + quad * 4;
#pragma unroll
            for (int r = 0; r < 4; ++r)
                H[(size_t)(rowb + r) * 256 + col] = (bf16_t)acc[mi][ni][r];
        }
#pragma unroll
    for (int ni = 0; ni < 2; ++ni) {
        float s = 0.0f, ss = 0.0f;
#pragma unroll
        for (int mi = 0; mi < 4; ++mi)
#pragma unroll
            for (int r = 0; r < 4; ++r) {
                float v = acc[mi][ni][r];
                s += v; ss = fmaf(v, v, ss);
            }
        s  += __shfl_xor(s, 16);  s  += __shfl_xor(s, 32);
        ss += __shfl_xor(ss, 16); ss += __shfl_xor(ss, 32);
        if (quad == 0) {
            int cl = w * 32 + ni * 16 + l15;
            float* slot = P1 + (size_t)blockIdx.x * 512;
            slot[cl]       = s;
            slot[256 + cl] = ss;
        }
    }
}

// ---------------- reduce per-block partials -> scale/shift (one block per channel) ----------------
__global__ __launch_bounds__(256) void finalize_partials_kernel(const float* __restrict__ P, int nblk,
                                                                const float* __restrict__ gamma,
                                                                const float* __restrict__ beta,
                                                                float* __restrict__ scale,
                                                                float* __restrict__ shift) {
    int c = blockIdx.x;
    float s = 0.0f, ss = 0.0f;
    for (int bb = threadIdx.x; bb < nblk; bb += 256) {
        const float* row = P + (size_t)bb * 512;
        s  += row[c];
        ss += row[256 + c];
    }
#pragma unroll
    for (int k = 32; k >= 1; k >>= 1) { s += __shfl_xor(s, k); ss += __shfl_xor(ss, k); }
    __shared__ float as_[4], ass_[4];
    int w = threadIdx.x >> 6;
    if ((threadIdx.x & 63) == 0) { as_[w] = s; ass_[w] = ss; }
    __syncthreads();
    if (threadIdx.x == 0) {
        float S  = as_[0] + as_[1] + as_[2] + as_[3];
        float SS = ass_[0] + ass_[1] + ass_[2] + ass_[3];
        float m   = S * (1.0f / NP);
        float var = SS * (1.0f / NP) - m * m;
        float sc  = rsqrtf(var + 1e-5f) * gamma[c];
        scale[c] = sc;
        shift[c] = fmaf(-m, sc, beta[c]);
    }
}

// ---------------- final BN+ReLU: H1 bf16 -> fp32 d_out ----------------
__global__ void bnrelu_final_kernel(const bf16_t* __restrict__ H, const float* __restrict__ scale,
                                    const float* __restrict__ shift, float* __restrict__ out) {
    int tid = blockIdx.x * 256 + threadIdx.x;
    bf16x8 v = *(const bf16x8*)(H + (size_t)tid * 8);
    int c = (tid & 31) * 8;
    float4 o0, o1;
    o0.x = fmaxf(fmaf((float)v[0], scale[c + 0], shift[c + 0]), 0.0f);
    o0.y = fmaxf(fmaf((float)v[1], scale[c + 1], shift[c + 1]), 0.0f);
    o0.z = fmaxf(fmaf((float)v[2], scale[c + 2], shift[c + 2]), 0.0f);
    o0.w = fmaxf(fmaf((float)v[3], scale[c + 3], shift[c + 3]), 0.0f);
    o1.x = fmaxf(fmaf((float)v[4], scale[c + 4], shift[c + 4]), 0.0f);
    o1.y = fmaxf(fmaf((float)v[5], scale[c + 5], shift[c + 5]), 0.0f);
    o1.z = fmaxf(fmaf((float)v[6], scale[c + 6], shift[c + 6]), 0.0f);
    o1.w = fmaxf(fmaf((float)v[7], scale[c + 7], shift[c + 7]), 0.0f);
    ((float4*)out)[tid * 2]     = o0;
    ((float4*)out)[tid * 2 + 1] = o1;
}

extern "C" void kernel_launch(void* const* d_in, const int* in_sizes, int n_in,
                              void* d_out, int out_size, void* d_ws, size_t ws_size,
                              hipStream_t stream) {
    const float* xyz1    = (const float*)d_in[0];
    const float* xyz2    = (const float*)d_in[1];
    const float* points1 = (const float*)d_in[2];
    const float* points2 = (const float*)d_in[3];
    const float* W0      = (const float*)d_in[4];
    const float* g0      = (const float*)d_in[5];
    const float* b0      = (const float*)d_in[6];
    const float* W1      = (const float*)d_in[7];
    const float* g1      = (const float*)d_in[8];
    const float* b1      = (const float*)d_in[9];
    float* out = (float*)d_out;

    // ws layout (float offsets), ~85.8 MB
    float* wsf    = (float*)d_ws;
    float* scale0 = wsf + 0;
    float* shift0 = wsf + 256;
    float* scale1 = wsf + 512;
    float* shift1 = wsf + 768;
    float* w3     = wsf + 2048;                       // 196608 f
    int*   idx3   = (int*)(wsf + 198656);             // 196608 i
    bf16_t* Wb0   = (bf16_t*)(wsf + 395264);          // 98304 bf16
    bf16_t* Wb1   = (bf16_t*)(wsf + 444416);          // 65536 bf16
    float* pd     = wsf + 477184;                     // NP*24 f (dead after merge)
    int*   pi     = (int*)(wsf + 2050048);            // NP*24 i
    bf16_t* P2b   = (bf16_t*)(wsf + 477184);          // 4194304 bf16, aliases pd (cvt after merge)
    bf16_t* H0    = (bf16_t*)(wsf + 3622912);         // NP*256 bf16
    bf16_t* H1    = (bf16_t*)(wsf + 12011520);        // NP*256 bf16
    float* P0     = wsf + 20400128;                   // 1024*512 f
    float* P1     = wsf + 20924416;                   // 1024*512 f -> ends 21448704 f

    cvt_bf16_kernel<<<(M0 * CIN + 255) / 256, 256, 0, stream>>>(W0, Wb0, M0 * CIN);
    cvt_bf16_kernel<<<(M0 * M0 + 255) / 256, 256, 0, stream>>>(W1, Wb1, M0 * M0);

    nn3_partial_kernel<<<dim3(B_SZ * (N1 / 256), CHUNKS), 256, 0, stream>>>(xyz1, xyz2, pd, pi);
    nn3_merge_kernel<<<NP / 256, 256, 0, stream>>>(pd, pi, idx3, w3);

    // points2 -> bf16 (into the dead pd/pi region)
    cvt_bf16x4_kernel<<<(B_SZ * N2 * C2 / 4) / 256, 256, 0, stream>>>(points2, P2b);

    // layer 0
    gemm1_fused_kernel<<<NP / 64, 512, 0, stream>>>(points1, P2b, idx3, w3, Wb0, H0, P0);
    finalize_partials_kernel<<<256, 256, 0, stream>>>(P0, NP / 64, g0, b0, scale0, shift0);

    // layer 1
    gemm2_kernel<<<NP / 64, 512, 0, stream>>>(H0, Wb1, scale0, shift0, H1, P1);
    finalize_partials_kernel<<<256, 256, 0, stream>>>(P1, NP / 64, g1, b1, scale1, shift1);

    // final BN+ReLU -> fp32 output
    bnrelu_final_kernel<<<NP * 256 / 8 / 256, 256, 0, stream>>>(H1, scale1, shift1, out);
}